// Round 11
// baseline (229.718 us; speedup 1.0000x reference)
//
#include <hip/hip_runtime.h>
#include <hip/hip_bf16.h>
#include <stdint.h>
#include <math.h>

#define S_LEN   4096
#define D_MODEL 1024
#define NHEAD   16
#define DK      64

typedef __attribute__((ext_vector_type(8)))  __bf16 bf16x8;
typedef __attribute__((ext_vector_type(4)))  float  f32x4;
typedef __attribute__((ext_vector_type(16))) float  f32x16;
typedef __attribute__((ext_vector_type(4)))  unsigned int u32x4;
using bf16 = __hip_bfloat16;

__device__ __forceinline__ void load_lds16(const bf16* g, bf16* l) {
    __builtin_amdgcn_global_load_lds(
        (const __attribute__((address_space(1))) void*)g,
        (__attribute__((address_space(3))) void*)l, 16, 0, 0);
}

// ---------------- fused fp32 -> bf16 convert (x + 4 weights), 4 elems/thread ----------------
__global__ void cvt_all(const float* __restrict__ x,
                        const float* __restrict__ w0, const float* __restrict__ w1,
                        const float* __restrict__ w2, const float* __restrict__ w3,
                        bf16* __restrict__ xb,
                        bf16* __restrict__ b0, bf16* __restrict__ b1,
                        bf16* __restrict__ b2, bf16* __restrict__ b3)
{
    size_t i4 = ((size_t)blockIdx.x * 256 + threadIdx.x) * 4;
    const float* s; bf16* d; size_t off;
    const size_t NX = (size_t)S_LEN * D_MODEL;         // 4M
    const size_t NW = (size_t)D_MODEL * D_MODEL;       // 1M
    if (i4 < NX) { s = x; d = xb; off = i4; }
    else {
        size_t j = i4 - NX;
        int sel = (int)(j >> 20);
        off = j & (NW - 1);
        s = sel == 0 ? w0 : sel == 1 ? w1 : sel == 2 ? w2 : w3;
        d = sel == 0 ? b0 : sel == 1 ? b1 : sel == 2 ? b2 : b3;
    }
    float4 v = *(const float4*)&s[off];
    bf16 t[4] __attribute__((aligned(8)));
    t[0] = __float2bfloat16(v.x); t[1] = __float2bfloat16(v.y);
    t[2] = __float2bfloat16(v.z); t[3] = __float2bfloat16(v.w);
    *(uint64_t*)&d[off] = *(const uint64_t*)t;
}

// ---------------- RoPE cos/sin table: T[s][f] = (cos, sin)(pos[s] * 10000^(-f/32)) ----------------
// 4096 x 32 x 8B = 1 MB (L2-resident). Replaces 64 __sincosf per thread in the
// qkv epilogue (ocml range-reduction bloat) with one 8B load per element.
__global__ void rope_tab(const int* __restrict__ pos, float2* __restrict__ T)
{
    int i = blockIdx.x * 256 + threadIdx.x;    // 131072 entries
    int s = i >> 5, f = i & 31;
    float p   = (float)pos[s];
    float inv = __builtin_amdgcn_exp2f((float)f * (-0.41524101186092028f));
    float sn, cs;
    __sincosf(p * inv, &sn, &cs);
    T[i] = make_float2(cs, sn);
}

// ---------------- QKV GEMM with fused RoPE epilogue (table-driven) ----------------
// z = 0 -> Qb (bf16, roped, scaled by (1/8)*log2e), 1 -> Kb (bf16, roped),
// 2 -> VtG (bf16, transposed [D][S]).
__global__ __launch_bounds__(256) void qkv_gemm(
    const bf16* __restrict__ Xb,
    const bf16* __restrict__ Wq, const bf16* __restrict__ Wk, const bf16* __restrict__ Wv,
    const float2* __restrict__ Tb,
    bf16* __restrict__ Qb, bf16* __restrict__ Kb, bf16* __restrict__ VtG)
{
    const int K = D_MODEL, N = D_MODEL;
    int z = blockIdx.z;
    const bf16* B = (z == 0) ? Wq : (z == 1) ? Wk : Wv;

    __shared__ __align__(16) bf16 As[2][128 * 32];
    __shared__ __align__(16) bf16 Bs[2][128 * 32];
    __shared__ __align__(16) bf16 Ts[4][64 * 24];   // per-wave V-transpose strip (z=2)

    int row0 = blockIdx.y * 128;
    int col0 = blockIdx.x * 128;
    int tid  = threadIdx.x;
    int wv   = tid >> 6, lane = tid & 63;
    int m16  = lane & 15, quad = lane >> 4;
    int wr   = (wv >> 1) * 64, wc = (wv & 1) * 64;
    int l4   = lane >> 2, l3 = (lane & 3) * 8;

    const bf16* ga_base = Xb + (size_t)(row0 + wv * 16 + l4) * K + l3;
    const bf16* gb_base = B  + (size_t)(col0 + wv * 16 + l4) * K + l3;

    auto stage = [&](int k0, int buf) {
        load_lds16(ga_base + k0,            &As[buf][wv * 512]);
        load_lds16(ga_base + k0 + 64 * K,   &As[buf][2048 + wv * 512]);
        load_lds16(gb_base + k0,            &Bs[buf][wv * 512]);
        load_lds16(gb_base + k0 + 64 * K,   &Bs[buf][2048 + wv * 512]);
    };

    f32x4 acc[4][4];
    #pragma unroll
    for (int i = 0; i < 4; i++)
        #pragma unroll
        for (int j = 0; j < 4; j++) acc[i][j] = (f32x4){0.f, 0.f, 0.f, 0.f};

    stage(0, 0);
    for (int k0 = 0; k0 < K; k0 += 32) {
        __syncthreads();
        int buf = (k0 >> 5) & 1;
        if (k0 + 32 < K) stage(k0 + 32, buf ^ 1);
        bf16x8 a[4], b[4];
        #pragma unroll
        for (int mi = 0; mi < 4; mi++) a[mi] = *(const bf16x8*)&As[buf][(wr + mi * 16 + m16) * 32 + quad * 8];
        #pragma unroll
        for (int ni = 0; ni < 4; ni++) b[ni] = *(const bf16x8*)&Bs[buf][(wc + ni * 16 + m16) * 32 + quad * 8];
        #pragma unroll
        for (int mi = 0; mi < 4; mi++)
            #pragma unroll
            for (int ni = 0; ni < 4; ni++)
                acc[mi][ni] = __builtin_amdgcn_mfma_f32_16x16x32_bf16(a[mi], b[ni], acc[mi][ni], 0, 0, 0);
    }

    if (z < 2) {
        // table-driven RoPE -> bf16 (Q additionally scaled by (1/8)*log2e)
        bf16* O = (z == 0) ? Qb : Kb;
        const float qscale = (z == 0) ? 0.18033688011112042f : 1.0f;
        bool odd = (m16 & 1) != 0;
        int fbase = m16 >> 1;                    // pair index within head half
        #pragma unroll
        for (int mi = 0; mi < 4; mi++) {
            #pragma unroll
            for (int r = 0; r < 4; r++) {
                int gr = row0 + wr + mi * 16 + quad * 4 + r;
                const float2* Trow = Tb + (size_t)gr * 32 + fbase;
                #pragma unroll
                for (int ni = 0; ni < 4; ni++) {
                    float own   = acc[mi][ni][r];
                    float other = __shfl_xor(own, 1);   // col gc^1 partner
                    float2 cssn = Trow[ni * 8];         // (cos, sin), lane-pair broadcast
                    float x1 = odd ? other : own;
                    float x2 = odd ? own   : other;
                    float res = odd ? (x1 * cssn.y + x2 * cssn.x)
                                    : (x1 * cssn.x - x2 * cssn.y);
                    int gc = col0 + wc + ni * 16 + m16;
                    O[(size_t)gr * N + gc] = __float2bfloat16(res * qscale);
                }
            }
        }
    } else {
        // per-wave transpose through LDS, then coalesced 16B stores to VtG[gc][gr]
        #pragma unroll
        for (int mi = 0; mi < 4; mi++) {
            #pragma unroll
            for (int nt = 0; nt < 4; nt++) {
                bf16 t4[4] __attribute__((aligned(8)));
                #pragma unroll
                for (int r = 0; r < 4; r++) t4[r] = __float2bfloat16(acc[mi][nt][r]);
                *(uint64_t*)&Ts[wv][(nt * 16 + m16) * 24 + quad * 4] = *(const uint64_t*)t4;
            }
            #pragma unroll
            for (int rep = 0; rep < 2; rep++) {
                int c  = (lane >> 1) + rep * 32;
                int r8 = lane & 1;
                bf16x8 val = *(const bf16x8*)&Ts[wv][c * 24 + r8 * 8];
                int gc = col0 + wc + c;
                int gr = row0 + wr + mi * 16 + r8 * 8;
                *(bf16x8*)&VtG[(size_t)gc * S_LEN + gr] = val;
            }
        }
    }
}

// ---------------- Output GEMM: out = Attn(bf16) * Wo^T -> fp32 ----------------
// 128x64 tiles -> grid (16,32) = 512 blocks = 2 blocks/CU.
__global__ __launch_bounds__(256) void out_gemm(
    const bf16* __restrict__ A_, const bf16* __restrict__ B,
    float* __restrict__ C)
{
    const int K = D_MODEL, N = D_MODEL;
    __shared__ __align__(16) bf16 As[2][128 * 32];   // 16 KB
    __shared__ __align__(16) bf16 Bs[2][64 * 32];    //  8 KB

    int row0 = blockIdx.y * 128;
    int col0 = blockIdx.x * 64;
    int tid  = threadIdx.x;
    int wv   = tid >> 6, lane = tid & 63;
    int m16  = lane & 15, quad = lane >> 4;
    int wr   = (wv >> 1) * 64, wc = (wv & 1) * 32;   // 2x2 waves of 64x32
    int l4   = lane >> 2, l3 = (lane & 3) * 8;

    const bf16* ga_base = A_ + (size_t)(row0 + wv * 16 + l4) * K + l3;
    const bf16* gb_base = B  + (size_t)(col0 + wv * 16 + l4) * K + l3;  // rows 0..63

    auto stage = [&](int k0, int buf) {
        load_lds16(ga_base + k0,            &As[buf][wv * 512]);
        load_lds16(ga_base + k0 + 64 * K,   &As[buf][2048 + wv * 512]);
        load_lds16(gb_base + k0,            &Bs[buf][wv * 512]);
    };

    f32x4 acc[4][2];
    #pragma unroll
    for (int i = 0; i < 4; i++)
        #pragma unroll
        for (int j = 0; j < 2; j++) acc[i][j] = (f32x4){0.f, 0.f, 0.f, 0.f};

    stage(0, 0);
    for (int k0 = 0; k0 < K; k0 += 32) {
        __syncthreads();
        int buf = (k0 >> 5) & 1;
        if (k0 + 32 < K) stage(k0 + 32, buf ^ 1);
        bf16x8 a[4], b[2];
        #pragma unroll
        for (int mi = 0; mi < 4; mi++) a[mi] = *(const bf16x8*)&As[buf][(wr + mi * 16 + m16) * 32 + quad * 8];
        #pragma unroll
        for (int ni = 0; ni < 2; ni++) b[ni] = *(const bf16x8*)&Bs[buf][(wc + ni * 16 + m16) * 32 + quad * 8];
        #pragma unroll
        for (int mi = 0; mi < 4; mi++)
            #pragma unroll
            for (int ni = 0; ni < 2; ni++)
                acc[mi][ni] = __builtin_amdgcn_mfma_f32_16x16x32_bf16(a[mi], b[ni], acc[mi][ni], 0, 0, 0);
    }

    #pragma unroll
    for (int mi = 0; mi < 4; mi++)
        #pragma unroll
        for (int ni = 0; ni < 2; ni++)
            #pragma unroll
            for (int r = 0; r < 4; r++) {
                int gr = row0 + wr + mi * 16 + quad * 4 + r;
                int gc = col0 + wc + ni * 16 + m16;
                C[(size_t)gr * N + gc] = acc[mi][ni][r];
            }
}

// ---------------- Flash attention (unchanged from round 10, best-known) ----------------
// 32x32 MFMA + LDS staging: swapped QK^T with bit-2<->3-swapped K rows,
// in-register P via v_cvt_pk_bf16_f32, 2q x 2parity waves, additive parity
// combine, chunk-swizzled [64][64] K/V tiles, double-buffered global_load_lds,
// SHIFT folded into acc init, row sums via ones-MFMA, hoisted LDS bases.
__global__ __launch_bounds__(256, 4) void attn_kernel(
    const bf16* __restrict__ Qb, const bf16* __restrict__ Kb, const bf16* __restrict__ VtG,
    bf16* __restrict__ Attn)
{
    int bx  = blockIdx.x;
    int h   = bx & 15;
    int qt  = 63 - (bx >> 4);            // longest q-tiles first
    int tid = threadIdx.x;
    int wv  = tid >> 6, lane = tid & 63;
    int wq  = wv >> 1, wp = wv & 1;      // q-half / key-parity
    int l31 = lane & 31, hi = lane >> 5;
    int hc  = h * DK;
    int qs  = qt * 64 + wq * 32;         // this wave's first q-row
    int myq = qs + l31;

    // K A-frag row: bit2<->bit3 swap of l31 -> C-reg order matches PV A-frag
    int krow = (l31 & 19) | (((l31 >> 3) & 1) << 2) | (((l31 >> 2) & 1) << 3);
    int k7   = krow & 7;
    int d7   = l31 & 7;

    __shared__ __align__(16) bf16 KT[2][4096];   // [buf][key(64)][64 d, chunk-swz]  16 KB
    __shared__ __align__(16) bf16 VT[2][4096];   // [buf][d(64)][64 key, chunk-swz]  16 KB
    __shared__ float Lbuf[2][2][32];             // [wq][wp][q] parity row sums

    // staging: thread covers (row = wv*16 + 8i + (lane>>3), slot = lane&7);
    // source chunk = slot ^ (row&7) = (lane&7) ^ (lane>>3)  (involution)
    int srow = lane >> 3, schunk = (lane & 7) ^ srow;
    const bf16* kst = Kb  + (size_t)(wv * 16 + srow) * D_MODEL + hc + schunk * 8;
    const bf16* vst = VtG + (size_t)(hc + wv * 16 + srow) * S_LEN + schunk * 8;

    auto stage = [&](int t, int buf) {
        size_t kb64 = (size_t)t * 64;
        #pragma unroll
        for (int i = 0; i < 2; i++) {
            load_lds16(kst + (kb64 + 8 * i) * D_MODEL, &KT[buf][(wv * 16 + 8 * i) * 64]);
            load_lds16(vst + (size_t)(8 * i) * S_LEN + kb64, &VT[buf][(wv * 16 + 8 * i) * 64]);
        }
    };

    // hoisted per-buffer LDS read bases + XOR chunk offsets (loop-invariant)
    const bf16* ktb0 = &KT[0][(wp * 32 + krow) * 64];
    const bf16* ktb1 = &KT[1][(wp * 32 + krow) * 64];
    const bf16* vtb0 = &VT[0][l31 * 64];
    const bf16* vtb1 = &VT[1][l31 * 64];
    int koff[4];
    #pragma unroll
    for (int ks = 0; ks < 4; ks++) koff[ks] = ((ks * 2 + hi) ^ k7) * 8;
    int voff0 = ((wp * 4 + 0 + hi) ^ d7) * 8;
    int voff2 = ((wp * 4 + 2 + hi) ^ d7) * 8;

    // Q fragments (B operand), in registers for the whole loop
    const bf16* qbase = Qb + (size_t)(qs + l31) * D_MODEL + hc + hi * 8;
    bf16x8 aQ[4];
    #pragma unroll
    for (int d = 0; d < 4; d++) aQ[d] = *(const bf16x8*)&qbase[d * 16];

    // constant all-ones B fragment for the row-sum MFMA
    bf16x8 bone;
    #pragma unroll
    for (int j = 0; j < 8; j++) bone[j] = (__bf16)1.0f;

    f32x16 o0, o1, o_sum;                 // O[32 q][64 d] + row sums (matrix pipe)
    #pragma unroll
    for (int i = 0; i < 16; i++) { o0[i] = 0.f; o1[i] = 0.f; o_sum[i] = 0.f; }

    auto tile = [&](const bf16* ktb, const bf16* vtb, int kb, bool diag) {
        bf16x8 aK[4];
        #pragma unroll
        for (int ks = 0; ks < 4; ks++)
            aK[ks] = *(const bf16x8*)&ktb[koff[ks]];

        // s initialized to -SHIFT: exp2(s_final) == exp2(score - 8)
        f32x16 s;
        #pragma unroll
        for (int i = 0; i < 16; i++) s[i] = -8.0f;
        s = __builtin_amdgcn_mfma_f32_32x32x16_bf16(aK[0], aQ[0], s, 0, 0, 0);
        s = __builtin_amdgcn_mfma_f32_32x32x16_bf16(aK[1], aQ[1], s, 0, 0, 0);
        s = __builtin_amdgcn_mfma_f32_32x32x16_bf16(aK[2], aQ[2], s, 0, 0, 0);
        s = __builtin_amdgcn_mfma_f32_32x32x16_bf16(aK[3], aQ[3], s, 0, 0, 0);

        // p = exp2(s); reg r holds key kb + (r&3)+4*((r>>2)&1)+8*hi+16*(r>>3)
        float p[16];
        #pragma unroll
        for (int r = 0; r < 16; r++) {
            float pv = __builtin_amdgcn_exp2f(s[r]);
            if (diag) {
                int key = kb + (r & 3) + ((r >> 2) & 1) * 4 + hi * 8 + (r >> 3) * 16;
                if (key > myq) pv = 0.f;
            }
            p[r] = pv;
        }

        // pack to PV A-frags in-register (key order consecutive by construction)
        unsigned int w[8];
        #pragma unroll
        for (int i = 0; i < 8; i++)
            asm("v_cvt_pk_bf16_f32 %0, %1, %2" : "=v"(w[i]) : "v"(p[2 * i]), "v"(p[2 * i + 1]));
        u32x4 wa = {w[0], w[1], w[2], w[3]};
        u32x4 wb = {w[4], w[5], w[6], w[7]};
        bf16x8 aP0 = __builtin_bit_cast(bf16x8, wa);   // tile keys 0..15
        bf16x8 aP1 = __builtin_bit_cast(bf16x8, wb);   // tile keys 16..31

        // V fragments: row = d (l31 / 32+l31 via imm offset), parity key slices
        bf16x8 bV00 = *(const bf16x8*)&vtb[voff0];
        bf16x8 bV10 = *(const bf16x8*)&vtb[voff2];
        bf16x8 bV01 = *(const bf16x8*)&vtb[voff0 + 32 * 64];
        bf16x8 bV11 = *(const bf16x8*)&vtb[voff2 + 32 * 64];

        o0 = __builtin_amdgcn_mfma_f32_32x32x16_bf16(aP0, bV00, o0, 0, 0, 0);
        o0 = __builtin_amdgcn_mfma_f32_32x32x16_bf16(aP1, bV10, o0, 0, 0, 0);
        o1 = __builtin_amdgcn_mfma_f32_32x32x16_bf16(aP0, bV01, o1, 0, 0, 0);
        o1 = __builtin_amdgcn_mfma_f32_32x32x16_bf16(aP1, bV11, o1, 0, 0, 0);
        // row sums ride the matrix pipe (C[row=q][*] = sum over this tile's keys)
        o_sum = __builtin_amdgcn_mfma_f32_32x32x16_bf16(aP0, bone, o_sum, 0, 0, 0);
        o_sum = __builtin_amdgcn_mfma_f32_32x32x16_bf16(aP1, bone, o_sum, 0, 0, 0);
    };

    stage(0, 0);
    for (int t = 0; t <= qt; t += 2) {
        __syncthreads();                 // drains vmcnt -> stage(t) visible
        if (t < qt) stage(t + 1, 1);
        {
            int kb = t * 64 + wp * 32;
            if (kb <= qs) tile(ktb0, vtb0, kb, kb == qs);
        }
        if (t + 1 > qt) break;
        __syncthreads();
        if (t + 1 < qt) stage(t + 2, 0);
        {
            int kb = (t + 1) * 64 + wp * 32;
            if (kb <= qs) tile(ktb1, vtb1, kb, kb == qs);
        }
    }

    // ---- parity combine (Obuf overlays the dead K staging buffer, 16 KB) ----
    __syncthreads();                      // all waves done reading KT/VT
    #pragma unroll
    for (int r = 0; r < 16; r++) {
        int qr = (r & 3) + (r >> 2) * 8 + hi * 4;
        Lbuf[wq][wp][qr] = o_sum[r];      // all cols identical; redundant same-addr writes OK
    }
    float* Obuf = (float*)&KT[0][0];      // [wq][dt][reg][lane] = 2*2*16*64 f32
    if (wp == 1) {
        #pragma unroll
        for (int r = 0; r < 16; r++) {
            Obuf[((wq * 2 + 0) * 16 + r) * 64 + lane] = o0[r];
            Obuf[((wq * 2 + 1) * 16 + r) * 64 + lane] = o1[r];
        }
    }
    __syncthreads();
    if (wp == 0) {
        #pragma unroll
        for (int r = 0; r < 16; r++) {
            int qr = (r & 3) + (r >> 2) * 8 + hi * 4;   // C-layout q-row
            float lsum = Lbuf[wq][0][qr] + Lbuf[wq][1][qr];
            float inv  = 1.0f / lsum;
            float v0 = (o0[r] + Obuf[((wq * 2 + 0) * 16 + r) * 64 + lane]) * inv;
            float v1 = (o1[r] + Obuf[((wq * 2 + 1) * 16 + r) * 64 + lane]) * inv;
            bf16* dst = Attn + (size_t)(qs + qr) * D_MODEL + hc + l31;
            dst[0]  = __float2bfloat16(v0);
            dst[32] = __float2bfloat16(v1);
        }
    }
}

extern "C" void kernel_launch(void* const* d_in, const int* in_sizes, int n_in,
                              void* d_out, int out_size, void* d_ws, size_t ws_size,
                              hipStream_t stream)
{
    const float* x  = (const float*)d_in[0];
    const int*   pos= (const int*)d_in[1];
    const float* Wq = (const float*)d_in[2];
    const float* Wk = (const float*)d_in[3];
    const float* Wv = (const float*)d_in[4];
    const float* Wo = (const float*)d_in[5];
    float* out = (float*)d_out;

    char* ws = (char*)d_ws;
    bf16*   xb   = (bf16*)  (ws);                    // 8 MB
    bf16*   wqb  = (bf16*)  (ws + ( 8ull << 20));    // 2 MB
    bf16*   wkb  = (bf16*)  (ws + (10ull << 20));
    bf16*   wvb  = (bf16*)  (ws + (12ull << 20));
    bf16*   wob  = (bf16*)  (ws + (14ull << 20));
    bf16*   Qb   = (bf16*)  (ws + (16ull << 20));    // 8 MB (roped, scaled)
    bf16*   Kb   = (bf16*)  (ws + (24ull << 20));    // 8 MB (roped)
    bf16*   VtG  = (bf16*)  (ws + (32ull << 20));    // 8 MB (V transposed [D][S])
    bf16*   Attn = (bf16*)  (ws + (40ull << 20));    // 8 MB
    float2* Tbl  = (float2*)(ws + (48ull << 20));    // 1 MB -> 49 MB total

    cvt_all<<<8192, 256, 0, stream>>>(x, Wq, Wk, Wv, Wo, xb, wqb, wkb, wvb, wob);

    rope_tab<<<512, 256, 0, stream>>>(pos, Tbl);

    qkv_gemm<<<dim3(8, 32, 3), 256, 0, stream>>>(xb, wqb, wkb, wvb, Tbl, Qb, Kb, VtG);

    attn_kernel<<<dim3(1024), 256, 0, stream>>>(Qb, Kb, VtG, Attn);

    out_gemm<<<dim3(16, 32), 256, 0, stream>>>(Attn, wob, out);
}

// Round 12
// 202.471 us; speedup vs baseline: 1.1346x; 1.1346x over previous
//
#include <hip/hip_runtime.h>
#include <hip/hip_bf16.h>
#include <stdint.h>
#include <math.h>

#define S_LEN   4096
#define D_MODEL 1024
#define NHEAD   16
#define DK      64

typedef __attribute__((ext_vector_type(8)))  __bf16 bf16x8;
typedef __attribute__((ext_vector_type(4)))  float  f32x4;
typedef __attribute__((ext_vector_type(16))) float  f32x16;
typedef __attribute__((ext_vector_type(4)))  unsigned int u32x4;
using bf16 = __hip_bfloat16;

__device__ __forceinline__ void load_lds16(const bf16* g, bf16* l) {
    __builtin_amdgcn_global_load_lds(
        (const __attribute__((address_space(1))) void*)g,
        (__attribute__((address_space(3))) void*)l, 16, 0, 0);
}

// ---------------- fused fp32 -> bf16 convert (x + 4 weights), 4 elems/thread ----------------
__global__ void cvt_all(const float* __restrict__ x,
                        const float* __restrict__ w0, const float* __restrict__ w1,
                        const float* __restrict__ w2, const float* __restrict__ w3,
                        bf16* __restrict__ xb,
                        bf16* __restrict__ b0, bf16* __restrict__ b1,
                        bf16* __restrict__ b2, bf16* __restrict__ b3)
{
    size_t i4 = ((size_t)blockIdx.x * 256 + threadIdx.x) * 4;
    const float* s; bf16* d; size_t off;
    const size_t NX = (size_t)S_LEN * D_MODEL;         // 4M
    const size_t NW = (size_t)D_MODEL * D_MODEL;       // 1M
    if (i4 < NX) { s = x; d = xb; off = i4; }
    else {
        size_t j = i4 - NX;
        int sel = (int)(j >> 20);
        off = j & (NW - 1);
        s = sel == 0 ? w0 : sel == 1 ? w1 : sel == 2 ? w2 : w3;
        d = sel == 0 ? b0 : sel == 1 ? b1 : sel == 2 ? b2 : b3;
    }
    float4 v = *(const float4*)&s[off];
    bf16 t[4] __attribute__((aligned(8)));
    t[0] = __float2bfloat16(v.x); t[1] = __float2bfloat16(v.y);
    t[2] = __float2bfloat16(v.z); t[3] = __float2bfloat16(v.w);
    *(uint64_t*)&d[off] = *(const uint64_t*)t;
}

// ---------------- QKV GEMM with fused RoPE epilogue ----------------
// z = 0 -> Qb (bf16, roped, scaled by (1/8)*log2e), 1 -> Kb (bf16, roped),
// 2 -> VtG (bf16, transposed [D][S]).
// R11 post-mortem: table-driven RoPE regressed (scattered latency-exposed
// gathers at 3 blocks/CU) -> reverted to computed sincos (R10, proven).
// New: Ts (V-transpose strip) OVERLAYS the dead As buffer after the K-loop
// (one extra block-uniform barrier) -> LDS 52->32 KB -> 4 blocks/CU.
__global__ __launch_bounds__(256, 4) void qkv_gemm(
    const bf16* __restrict__ Xb,
    const bf16* __restrict__ Wq, const bf16* __restrict__ Wk, const bf16* __restrict__ Wv,
    const int* __restrict__ pos,
    bf16* __restrict__ Qb, bf16* __restrict__ Kb, bf16* __restrict__ VtG)
{
    const int K = D_MODEL, N = D_MODEL;
    int z = blockIdx.z;
    const bf16* B = (z == 0) ? Wq : (z == 1) ? Wk : Wv;

    __shared__ __align__(16) bf16 As[2][128 * 32];   // 16 KB (Ts overlays after loop)
    __shared__ __align__(16) bf16 Bs[2][128 * 32];   // 16 KB

    int row0 = blockIdx.y * 128;
    int col0 = blockIdx.x * 128;
    int tid  = threadIdx.x;
    int wv   = tid >> 6, lane = tid & 63;
    int m16  = lane & 15, quad = lane >> 4;
    int wr   = (wv >> 1) * 64, wc = (wv & 1) * 64;
    int l4   = lane >> 2, l3 = (lane & 3) * 8;

    const bf16* ga_base = Xb + (size_t)(row0 + wv * 16 + l4) * K + l3;
    const bf16* gb_base = B  + (size_t)(col0 + wv * 16 + l4) * K + l3;

    auto stage = [&](int k0, int buf) {
        load_lds16(ga_base + k0,            &As[buf][wv * 512]);
        load_lds16(ga_base + k0 + 64 * K,   &As[buf][2048 + wv * 512]);
        load_lds16(gb_base + k0,            &Bs[buf][wv * 512]);
        load_lds16(gb_base + k0 + 64 * K,   &Bs[buf][2048 + wv * 512]);
    };

    f32x4 acc[4][4];
    #pragma unroll
    for (int i = 0; i < 4; i++)
        #pragma unroll
        for (int j = 0; j < 4; j++) acc[i][j] = (f32x4){0.f, 0.f, 0.f, 0.f};

    stage(0, 0);
    for (int k0 = 0; k0 < K; k0 += 32) {
        __syncthreads();
        int buf = (k0 >> 5) & 1;
        if (k0 + 32 < K) stage(k0 + 32, buf ^ 1);
        bf16x8 a[4], b[4];
        #pragma unroll
        for (int mi = 0; mi < 4; mi++) a[mi] = *(const bf16x8*)&As[buf][(wr + mi * 16 + m16) * 32 + quad * 8];
        #pragma unroll
        for (int ni = 0; ni < 4; ni++) b[ni] = *(const bf16x8*)&Bs[buf][(wc + ni * 16 + m16) * 32 + quad * 8];
        #pragma unroll
        for (int mi = 0; mi < 4; mi++)
            #pragma unroll
            for (int ni = 0; ni < 4; ni++)
                acc[mi][ni] = __builtin_amdgcn_mfma_f32_16x16x32_bf16(a[mi], b[ni], acc[mi][ni], 0, 0, 0);
    }

    if (z < 2) {
        // computed-sincos RoPE -> bf16 (Q additionally scaled by (1/8)*log2e
        // so attention can use raw v_exp_f32 in base 2)
        bf16* O = (z == 0) ? Qb : Kb;
        const float qscale = (z == 0) ? 0.18033688011112042f : 1.0f;
        float invf[4];
        #pragma unroll
        for (int ni = 0; ni < 4; ni++) {
            float fi = (float)((ni * 16 + m16) >> 1);
            invf[ni] = __builtin_amdgcn_exp2f(fi * (-0.41524101186092028f));  // 10000^(-fi/32)
        }
        bool odd = (m16 & 1) != 0;
        #pragma unroll
        for (int mi = 0; mi < 4; mi++) {
            #pragma unroll
            for (int r = 0; r < 4; r++) {
                int gr = row0 + wr + mi * 16 + quad * 4 + r;
                float p = (float)pos[gr];
                #pragma unroll
                for (int ni = 0; ni < 4; ni++) {
                    float own   = acc[mi][ni][r];
                    float other = __shfl_xor(own, 1);   // col gc^1 partner
                    float sn, cs;
                    __sincosf(p * invf[ni], &sn, &cs);
                    float x1 = odd ? other : own;
                    float x2 = odd ? own   : other;
                    float res = odd ? (x1 * sn + x2 * cs) : (x1 * cs - x2 * sn);
                    int gc = col0 + wc + ni * 16 + m16;
                    O[(size_t)gr * N + gc] = __float2bfloat16(res * qscale);
                }
            }
        }
    } else {
        // per-wave transpose through LDS (Ts overlays dead As), then coalesced
        // 16B stores to VtG[gc][gr]. Barrier: all waves done reading As/Bs.
        __syncthreads();                          // block-uniform branch (z per block)
        bf16* Tsw = ((bf16*)As) + wv * 1536;      // 4 waves x 1536 elems = 12 KB
        #pragma unroll
        for (int mi = 0; mi < 4; mi++) {
            #pragma unroll
            for (int nt = 0; nt < 4; nt++) {
                bf16 t4[4] __attribute__((aligned(8)));
                #pragma unroll
                for (int r = 0; r < 4; r++) t4[r] = __float2bfloat16(acc[mi][nt][r]);
                *(uint64_t*)&Tsw[(nt * 16 + m16) * 24 + quad * 4] = *(const uint64_t*)t4;
            }
            #pragma unroll
            for (int rep = 0; rep < 2; rep++) {
                int c  = (lane >> 1) + rep * 32;
                int r8 = lane & 1;
                bf16x8 val = *(const bf16x8*)&Tsw[c * 24 + r8 * 8];
                int gc = col0 + wc + c;
                int gr = row0 + wr + mi * 16 + r8 * 8;
                *(bf16x8*)&VtG[(size_t)gc * S_LEN + gr] = val;
            }
        }
    }
}

// ---------------- Output GEMM: out = Attn(bf16) * Wo^T -> fp32 ----------------
// 64x64 tiles -> grid (16,64) = 1024 blocks = 4 blocks/CU (was 512 = 2/CU;
// latency-bound small GEMM -> occupancy dominates per-wave ILP ratio).
__global__ __launch_bounds__(256, 4) void out_gemm(
    const bf16* __restrict__ A_, const bf16* __restrict__ B,
    float* __restrict__ C)
{
    const int K = D_MODEL, N = D_MODEL;
    __shared__ __align__(16) bf16 As[2][64 * 32];    // 8 KB
    __shared__ __align__(16) bf16 Bs[2][64 * 32];    // 8 KB

    int row0 = blockIdx.y * 64;
    int col0 = blockIdx.x * 64;
    int tid  = threadIdx.x;
    int wv   = tid >> 6, lane = tid & 63;
    int m16  = lane & 15, quad = lane >> 4;
    int wr   = (wv >> 1) * 32, wc = (wv & 1) * 32;   // 2x2 waves of 32x32
    int l4   = lane >> 2, l3 = (lane & 3) * 8;

    const bf16* ga_base = A_ + (size_t)(row0 + wv * 16 + l4) * K + l3;
    const bf16* gb_base = B  + (size_t)(col0 + wv * 16 + l4) * K + l3;

    auto stage = [&](int k0, int buf) {
        load_lds16(ga_base + k0, &As[buf][wv * 512]);
        load_lds16(gb_base + k0, &Bs[buf][wv * 512]);
    };

    f32x4 acc[2][2];
    #pragma unroll
    for (int i = 0; i < 2; i++)
        #pragma unroll
        for (int j = 0; j < 2; j++) acc[i][j] = (f32x4){0.f, 0.f, 0.f, 0.f};

    stage(0, 0);
    for (int k0 = 0; k0 < K; k0 += 32) {
        __syncthreads();
        int buf = (k0 >> 5) & 1;
        if (k0 + 32 < K) stage(k0 + 32, buf ^ 1);
        bf16x8 a[2], b[2];
        #pragma unroll
        for (int mi = 0; mi < 2; mi++) a[mi] = *(const bf16x8*)&As[buf][(wr + mi * 16 + m16) * 32 + quad * 8];
        #pragma unroll
        for (int ni = 0; ni < 2; ni++) b[ni] = *(const bf16x8*)&Bs[buf][(wc + ni * 16 + m16) * 32 + quad * 8];
        #pragma unroll
        for (int mi = 0; mi < 2; mi++)
            #pragma unroll
            for (int ni = 0; ni < 2; ni++)
                acc[mi][ni] = __builtin_amdgcn_mfma_f32_16x16x32_bf16(a[mi], b[ni], acc[mi][ni], 0, 0, 0);
    }

    #pragma unroll
    for (int mi = 0; mi < 2; mi++)
        #pragma unroll
        for (int ni = 0; ni < 2; ni++)
            #pragma unroll
            for (int r = 0; r < 4; r++) {
                int gr = row0 + wr + mi * 16 + quad * 4 + r;
                int gc = col0 + wc + ni * 16 + m16;
                C[(size_t)gr * N + gc] = acc[mi][ni][r];
            }
}

// ---------------- Flash attention (unchanged from round 10, best-known) ----------------
// 32x32 MFMA + LDS staging: swapped QK^T with bit-2<->3-swapped K rows,
// in-register P via v_cvt_pk_bf16_f32, 2q x 2parity waves, additive parity
// combine, chunk-swizzled [64][64] K/V tiles, double-buffered global_load_lds,
// SHIFT folded into acc init, row sums via ones-MFMA, hoisted LDS bases.
__global__ __launch_bounds__(256, 4) void attn_kernel(
    const bf16* __restrict__ Qb, const bf16* __restrict__ Kb, const bf16* __restrict__ VtG,
    bf16* __restrict__ Attn)
{
    int bx  = blockIdx.x;
    int h   = bx & 15;
    int qt  = 63 - (bx >> 4);            // longest q-tiles first
    int tid = threadIdx.x;
    int wv  = tid >> 6, lane = tid & 63;
    int wq  = wv >> 1, wp = wv & 1;      // q-half / key-parity
    int l31 = lane & 31, hi = lane >> 5;
    int hc  = h * DK;
    int qs  = qt * 64 + wq * 32;         // this wave's first q-row
    int myq = qs + l31;

    // K A-frag row: bit2<->bit3 swap of l31 -> C-reg order matches PV A-frag
    int krow = (l31 & 19) | (((l31 >> 3) & 1) << 2) | (((l31 >> 2) & 1) << 3);
    int k7   = krow & 7;
    int d7   = l31 & 7;

    __shared__ __align__(16) bf16 KT[2][4096];   // [buf][key(64)][64 d, chunk-swz]  16 KB
    __shared__ __align__(16) bf16 VT[2][4096];   // [buf][d(64)][64 key, chunk-swz]  16 KB
    __shared__ float Lbuf[2][2][32];             // [wq][wp][q] parity row sums

    // staging: thread covers (row = wv*16 + 8i + (lane>>3), slot = lane&7);
    // source chunk = slot ^ (row&7) = (lane&7) ^ (lane>>3)  (involution)
    int srow = lane >> 3, schunk = (lane & 7) ^ srow;
    const bf16* kst = Kb  + (size_t)(wv * 16 + srow) * D_MODEL + hc + schunk * 8;
    const bf16* vst = VtG + (size_t)(hc + wv * 16 + srow) * S_LEN + schunk * 8;

    auto stage = [&](int t, int buf) {
        size_t kb64 = (size_t)t * 64;
        #pragma unroll
        for (int i = 0; i < 2; i++) {
            load_lds16(kst + (kb64 + 8 * i) * D_MODEL, &KT[buf][(wv * 16 + 8 * i) * 64]);
            load_lds16(vst + (size_t)(8 * i) * S_LEN + kb64, &VT[buf][(wv * 16 + 8 * i) * 64]);
        }
    };

    // hoisted per-buffer LDS read bases + XOR chunk offsets (loop-invariant)
    const bf16* ktb0 = &KT[0][(wp * 32 + krow) * 64];
    const bf16* ktb1 = &KT[1][(wp * 32 + krow) * 64];
    const bf16* vtb0 = &VT[0][l31 * 64];
    const bf16* vtb1 = &VT[1][l31 * 64];
    int koff[4];
    #pragma unroll
    for (int ks = 0; ks < 4; ks++) koff[ks] = ((ks * 2 + hi) ^ k7) * 8;
    int voff0 = ((wp * 4 + 0 + hi) ^ d7) * 8;
    int voff2 = ((wp * 4 + 2 + hi) ^ d7) * 8;

    // Q fragments (B operand), in registers for the whole loop
    const bf16* qbase = Qb + (size_t)(qs + l31) * D_MODEL + hc + hi * 8;
    bf16x8 aQ[4];
    #pragma unroll
    for (int d = 0; d < 4; d++) aQ[d] = *(const bf16x8*)&qbase[d * 16];

    // constant all-ones B fragment for the row-sum MFMA
    bf16x8 bone;
    #pragma unroll
    for (int j = 0; j < 8; j++) bone[j] = (__bf16)1.0f;

    f32x16 o0, o1, o_sum;                 // O[32 q][64 d] + row sums (matrix pipe)
    #pragma unroll
    for (int i = 0; i < 16; i++) { o0[i] = 0.f; o1[i] = 0.f; o_sum[i] = 0.f; }

    auto tile = [&](const bf16* ktb, const bf16* vtb, int kb, bool diag) {
        bf16x8 aK[4];
        #pragma unroll
        for (int ks = 0; ks < 4; ks++)
            aK[ks] = *(const bf16x8*)&ktb[koff[ks]];

        // s initialized to -SHIFT: exp2(s_final) == exp2(score - 8)
        f32x16 s;
        #pragma unroll
        for (int i = 0; i < 16; i++) s[i] = -8.0f;
        s = __builtin_amdgcn_mfma_f32_32x32x16_bf16(aK[0], aQ[0], s, 0, 0, 0);
        s = __builtin_amdgcn_mfma_f32_32x32x16_bf16(aK[1], aQ[1], s, 0, 0, 0);
        s = __builtin_amdgcn_mfma_f32_32x32x16_bf16(aK[2], aQ[2], s, 0, 0, 0);
        s = __builtin_amdgcn_mfma_f32_32x32x16_bf16(aK[3], aQ[3], s, 0, 0, 0);

        // p = exp2(s); reg r holds key kb + (r&3)+4*((r>>2)&1)+8*hi+16*(r>>3)
        float p[16];
        #pragma unroll
        for (int r = 0; r < 16; r++) {
            float pv = __builtin_amdgcn_exp2f(s[r]);
            if (diag) {
                int key = kb + (r & 3) + ((r >> 2) & 1) * 4 + hi * 8 + (r >> 3) * 16;
                if (key > myq) pv = 0.f;
            }
            p[r] = pv;
        }

        // pack to PV A-frags in-register (key order consecutive by construction)
        unsigned int w[8];
        #pragma unroll
        for (int i = 0; i < 8; i++)
            asm("v_cvt_pk_bf16_f32 %0, %1, %2" : "=v"(w[i]) : "v"(p[2 * i]), "v"(p[2 * i + 1]));
        u32x4 wa = {w[0], w[1], w[2], w[3]};
        u32x4 wb = {w[4], w[5], w[6], w[7]};
        bf16x8 aP0 = __builtin_bit_cast(bf16x8, wa);   // tile keys 0..15
        bf16x8 aP1 = __builtin_bit_cast(bf16x8, wb);   // tile keys 16..31

        // V fragments: row = d (l31 / 32+l31 via imm offset), parity key slices
        bf16x8 bV00 = *(const bf16x8*)&vtb[voff0];
        bf16x8 bV10 = *(const bf16x8*)&vtb[voff2];
        bf16x8 bV01 = *(const bf16x8*)&vtb[voff0 + 32 * 64];
        bf16x8 bV11 = *(const bf16x8*)&vtb[voff2 + 32 * 64];

        o0 = __builtin_amdgcn_mfma_f32_32x32x16_bf16(aP0, bV00, o0, 0, 0, 0);
        o0 = __builtin_amdgcn_mfma_f32_32x32x16_bf16(aP1, bV10, o0, 0, 0, 0);
        o1 = __builtin_amdgcn_mfma_f32_32x32x16_bf16(aP0, bV01, o1, 0, 0, 0);
        o1 = __builtin_amdgcn_mfma_f32_32x32x16_bf16(aP1, bV11, o1, 0, 0, 0);
        // row sums ride the matrix pipe (C[row=q][*] = sum over this tile's keys)
        o_sum = __builtin_amdgcn_mfma_f32_32x32x16_bf16(aP0, bone, o_sum, 0, 0, 0);
        o_sum = __builtin_amdgcn_mfma_f32_32x32x16_bf16(aP1, bone, o_sum, 0, 0, 0);
    };

    stage(0, 0);
    for (int t = 0; t <= qt; t += 2) {
        __syncthreads();                 // drains vmcnt -> stage(t) visible
        if (t < qt) stage(t + 1, 1);
        {
            int kb = t * 64 + wp * 32;
            if (kb <= qs) tile(ktb0, vtb0, kb, kb == qs);
        }
        if (t + 1 > qt) break;
        __syncthreads();
        if (t + 1 < qt) stage(t + 2, 0);
        {
            int kb = (t + 1) * 64 + wp * 32;
            if (kb <= qs) tile(ktb1, vtb1, kb, kb == qs);
        }
    }

    // ---- parity combine (Obuf overlays the dead K staging buffer, 16 KB) ----
    __syncthreads();                      // all waves done reading KT/VT
    #pragma unroll
    for (int r = 0; r < 16; r++) {
        int qr = (r & 3) + (r >> 2) * 8 + hi * 4;
        Lbuf[wq][wp][qr] = o_sum[r];      // all cols identical; redundant same-addr writes OK
    }
    float* Obuf = (float*)&KT[0][0];      // [wq][dt][reg][lane] = 2*2*16*64 f32
    if (wp == 1) {
        #pragma unroll
        for (int r = 0; r < 16; r++) {
            Obuf[((wq * 2 + 0) * 16 + r) * 64 + lane] = o0[r];
            Obuf[((wq * 2 + 1) * 16 + r) * 64 + lane] = o1[r];
        }
    }
    __syncthreads();
    if (wp == 0) {
        #pragma unroll
        for (int r = 0; r < 16; r++) {
            int qr = (r & 3) + (r >> 2) * 8 + hi * 4;   // C-layout q-row
            float lsum = Lbuf[wq][0][qr] + Lbuf[wq][1][qr];
            float inv  = 1.0f / lsum;
            float v0 = (o0[r] + Obuf[((wq * 2 + 0) * 16 + r) * 64 + lane]) * inv;
            float v1 = (o1[r] + Obuf[((wq * 2 + 1) * 16 + r) * 64 + lane]) * inv;
            bf16* dst = Attn + (size_t)(qs + qr) * D_MODEL + hc + l31;
            dst[0]  = __float2bfloat16(v0);
            dst[32] = __float2bfloat16(v1);
        }
    }
}

extern "C" void kernel_launch(void* const* d_in, const int* in_sizes, int n_in,
                              void* d_out, int out_size, void* d_ws, size_t ws_size,
                              hipStream_t stream)
{
    const float* x  = (const float*)d_in[0];
    const int*   pos= (const int*)d_in[1];
    const float* Wq = (const float*)d_in[2];
    const float* Wk = (const float*)d_in[3];
    const float* Wv = (const float*)d_in[4];
    const float* Wo = (const float*)d_in[5];
    float* out = (float*)d_out;

    char* ws = (char*)d_ws;
    bf16*  xb   = (bf16*) (ws);                    // 8 MB
    bf16*  wqb  = (bf16*) (ws + ( 8ull << 20));    // 2 MB
    bf16*  wkb  = (bf16*) (ws + (10ull << 20));
    bf16*  wvb  = (bf16*) (ws + (12ull << 20));
    bf16*  wob  = (bf16*) (ws + (14ull << 20));
    bf16*  Qb   = (bf16*) (ws + (16ull << 20));    // 8 MB (roped, scaled)
    bf16*  Kb   = (bf16*) (ws + (24ull << 20));    // 8 MB (roped)
    bf16*  VtG  = (bf16*) (ws + (32ull << 20));    // 8 MB (V transposed [D][S])
    bf16*  Attn = (bf16*) (ws + (40ull << 20));    // 8 MB -> 48 MB total

    cvt_all<<<8192, 256, 0, stream>>>(x, Wq, Wk, Wv, Wo, xb, wqb, wkb, wvb, wob);

    qkv_gemm<<<dim3(8, 32, 3), 256, 0, stream>>>(xb, wqb, wkb, wvb, pos, Qb, Kb, VtG);

    attn_kernel<<<dim3(1024), 256, 0, stream>>>(Qb, Kb, VtG, Attn);

    out_gemm<<<dim3(16, 64), 256, 0, stream>>>(Attn, wob, out);
}